// Round 3
// baseline (226.499 us; speedup 1.0000x reference)
//
#include <hip/hip_runtime.h>
#include <hip/hip_bf16.h>
#include <stdint.h>

// PSM cosine cost volume, MI355X (gfx950).
// out[b,d,h,w] = (1/C) * sum_c L[b,c,h,w] * R[b,c,h,w-d],  0 where w<d.
// Banded Gram matrix via bf16 MFMA 16x16x32. One block per (b,h,half-row).
//
// LDS layout (per tile row lw, 128B = 64 bf16 = KC channels):
//   slot  (16B) = (chi ^ (lw&7)) where chi = c>>3        [read-conflict swizzle]
//   dword (4B)  = ((cpair&3) + ((lw>>4)&3)) & 3          [write-conflict rotation]
// Rotation is lane-uniform per 16-row fragment tile (rot = tile index & 3), so a
// uniform k-permutation applies to both MFMA operands and cancels; the A-side
// relative rotation (jj&3) is undone at read via template-dispatched patterns.

#define B_ 4
#define C_ 512
#define H_ 96
#define W_ 312
#define D_ 48
#define HW_ (H_ * W_)      // 29952
#define CHW_ (C_ * HW_)

#define KC 64              // staged c per chunk
#define NCHUNK (C_ / KC)   // 8
#define HALFW 156          // output w span per block
#define LCOLS 160          // staged L columns (10 N-tiles of 16)
#define RCOLS 208          // staged R columns ([wb-48, wb+160))
#define PITCH 128          // LDS row pitch bytes (64 bf16 = KC)
#define LBYTES (LCOLS * PITCH)          // 20480
#define RBYTES (RCOLS * PITCH)          // 26624
#define SMEM_BYTES (LBYTES + RBYTES)    // 47104 -> 3 blocks/CU

typedef __bf16 bf16x8 __attribute__((ext_vector_type(8)));
typedef float  f32x4  __attribute__((ext_vector_type(4)));
typedef uint32_t u32x2 __attribute__((ext_vector_type(2)));
typedef uint32_t u32x4 __attribute__((ext_vector_type(4)));

__device__ __forceinline__ uint32_t pack2_bf16(float a, float b) {
    // RNE f32 -> bf16 pair (a = low half = even c)
    uint32_t ua = __builtin_bit_cast(uint32_t, a);
    uint32_t ub = __builtin_bit_cast(uint32_t, b);
    ua += 0x7FFFu + ((ua >> 16) & 1u);
    ub += 0x7FFFu + ((ub >> 16) & 1u);
    return (ua >> 16) | (ub & 0xFFFF0000u);
}

__device__ __forceinline__ int lds_off(int lw, int rp) {
    // rp = c-pair index 0..31; chi = rp>>2; rotated dword position
    return lw * PITCH + (((rp >> 2) ^ (lw & 7)) << 4)
         + (((rp & 3) + ((lw >> 4) & 3)) & 3) * 4;
}

template<int JJ>
__device__ __forceinline__ void compute_chunk(const char* smem, int l15, int l4,
                                              int nb, f32x4* acc) {
    #pragma unroll
    for (int ks = 0; ks < 2; ++ks) {
        const int chi  = ks * 4 + l4;
        const int slot = (chi ^ (l15 & 7)) << 4;   // lw&7 == l15&7 for 16-row tiles
        #pragma unroll
        for (int pi = 0; pi < 5; ++pi) {
            const int n   = 2 * pi + nb;
            const int lwB = 16 * n + l15;
            const int lwA = lwB + 16 * JJ;
            bf16x8 bfrag = *(const bf16x8*)(smem + lwB * PITCH + slot);
            const char* ap = smem + LBYTES + lwA * PITCH + slot;
            u32x4 av;
            if constexpr (JJ == 0) {
                av = *(const u32x4*)ap;
            } else if constexpr (JJ == 2) {
                u32x2 lo = *(const u32x2*)(ap + 8);
                u32x2 hi = *(const u32x2*)(ap + 0);
                av = u32x4{lo.x, lo.y, hi.x, hi.y};
            } else {
                av.x = *(const uint32_t*)(ap + (((0 + JJ) & 3) << 2));
                av.y = *(const uint32_t*)(ap + (((1 + JJ) & 3) << 2));
                av.z = *(const uint32_t*)(ap + (((2 + JJ) & 3) << 2));
                av.w = *(const uint32_t*)(ap + (((3 + JJ) & 3) << 2));
            }
            bf16x8 afrag = __builtin_bit_cast(bf16x8, av);
            acc[pi] = __builtin_amdgcn_mfma_f32_16x16x32_bf16(afrag, bfrag, acc[pi], 0, 0, 0);
        }
    }
}

__global__ __launch_bounds__(512, 4)
void psm_cost_volume(const float* __restrict__ lf,
                     const float* __restrict__ rf,
                     float* __restrict__ out) {
    const int half = blockIdx.x;        // 0,1
    const int h    = blockIdx.y;
    const int b    = blockIdx.z;
    const int wb   = half * HALFW;
    const int tid  = threadIdx.x;
    const int lane = tid & 63;
    const int wave = tid >> 6;          // 8 waves
    const int l15  = lane & 15;
    const int l4   = lane >> 4;
    const int jj   = wave & 3;          // A-tile offset (relative rotation)
    const int nb   = wave >> 2;         // n = 2*pi + nb

    extern __shared__ char smem[];

    const float* lbase = lf + (size_t)b * CHW_ + (size_t)h * W_;
    const float* rbase = rf + (size_t)b * CHW_ + (size_t)h * W_;

    f32x4 acc[5];
    #pragma unroll
    for (int i = 0; i < 5; ++i) acc[i] = f32x4{0.f, 0.f, 0.f, 0.f};

    for (int ch = 0; ch < NCHUNK; ++ch) {
        const int c0 = ch * KC;
        if (ch) __syncthreads();   // previous compute done before restage

        // ---- stage L: 32 c-pairs x 160 w, lanes stride-1 in w ----
        #pragma unroll
        for (int it = 0; it < 10; ++it) {
            int idx = it * 512 + tid;
            int rp  = idx / LCOLS;
            int lw  = idx - rp * LCOLS;
            int w4  = wb + lw;
            float a0 = 0.f, a1 = 0.f;
            if (w4 < W_) {
                const float* g = lbase + (size_t)(c0 + 2 * rp) * HW_ + w4;
                a0 = g[0];
                a1 = g[HW_];
            }
            *(uint32_t*)(smem + lds_off(lw, rp)) = pack2_bf16(a0, a1);
        }
        // ---- stage R: 32 c-pairs x 208 w' ----
        #pragma unroll
        for (int it = 0; it < 13; ++it) {
            int idx = it * 512 + tid;
            int rp  = idx / RCOLS;
            int lw  = idx - rp * RCOLS;
            int w4  = wb - 48 + lw;
            float a0 = 0.f, a1 = 0.f;
            if (w4 >= 0 && w4 < W_) {
                const float* g = rbase + (size_t)(c0 + 2 * rp) * HW_ + w4;
                a0 = g[0];
                a1 = g[HW_];
            }
            *(uint32_t*)(smem + LBYTES + lds_off(lw, rp)) = pack2_bf16(a0, a1);
        }
        __syncthreads();

        // ---- compute: wave-uniform jj dispatch (barrier-free inside) ----
        switch (jj) {
            case 0:  compute_chunk<0>(smem, l15, l4, nb, acc); break;
            case 1:  compute_chunk<1>(smem, l15, l4, nb, acc); break;
            case 2:  compute_chunk<2>(smem, l15, l4, nb, acc); break;
            default: compute_chunk<3>(smem, l15, l4, nb, acc); break;
        }
    }
    __syncthreads();

    // ---- scatter accumulators -> LDS [D_][HALFW] f32 ----
    // D[m][n]: col tn = l15, row tm = 4*l4 + r.
    // w = wb + 16n + tn ; w' = wb - 48 + 16(n+jj) + tm ; d = 48 - 16*jj + tn - tm
    float* outs = (float*)smem;
    #pragma unroll
    for (int pi = 0; pi < 5; ++pi) {
        const int n  = 2 * pi + nb;
        const int lw = 16 * n + l15;
        #pragma unroll
        for (int r = 0; r < 4; ++r) {
            int tm = 4 * l4 + r;
            int d  = 48 - 16 * jj + l15 - tm;
            if (d >= 0 && d < D_ && lw < HALFW) {
                outs[d * HALFW + lw] = acc[pi][r] * (1.f / 512.f);
            }
        }
    }
    __syncthreads();

    // ---- coalesced global store ----
    float* obase = out + (size_t)b * (D_ * HW_) + (size_t)h * W_ + wb;
    for (int idx = tid; idx < D_ * HALFW; idx += 512) {
        int d  = idx / HALFW;
        int lw = idx - d * HALFW;
        obase[(size_t)d * HW_ + lw] = outs[idx];
    }
}

extern "C" void kernel_launch(void* const* d_in, const int* in_sizes, int n_in,
                              void* d_out, int out_size, void* d_ws, size_t ws_size,
                              hipStream_t stream) {
    const float* lf = (const float*)d_in[0];
    const float* rf = (const float*)d_in[1];
    float* out = (float*)d_out;
    dim3 grid(2, H_, B_);   // 768 blocks
    psm_cost_volume<<<grid, 512, SMEM_BYTES, stream>>>(lf, rf, out);
}

// Round 4
// 121.849 us; speedup vs baseline: 1.8589x; 1.8589x over previous
//
#include <hip/hip_runtime.h>
#include <hip/hip_bf16.h>
#include <stdint.h>

// PSM cosine cost volume, MI355X (gfx950).
// out[b,d,h,w] = (1/C) * sum_c L[b,c,h,w] * R[b,c,h,w-d],  0 where w<d.
// Banded Gram matrix via bf16 MFMA 16x16x32. One block per (b,h,half-row).
//
// LDS layout, per row lw (128B = 64 bf16 = KC channels), 16B slot s holds
// c in [8s',8s'+8) where s = s' ^ (lw&7) ^ ((lw>>4)&7):
//   - (lw&7) XOR: read-side spread (16 rows per fragment read)
//   - ((lw>>4)&7) XOR: write-side spread (lanes span w-tiles while staging);
//     wave-uniform at read time (tile index), so reads remain ds_read_b128.
// Dword within slot = c-pair index (rp&3); bf16 pair = (even c, odd c).

#define B_ 4
#define C_ 512
#define H_ 96
#define W_ 312
#define D_ 48
#define HW_ (H_ * W_)      // 29952
#define CHW_ (C_ * HW_)

#define KC 64              // staged c per chunk
#define NCHUNK (C_ / KC)   // 8
#define HALFW 156          // output w span per block
#define LCOLS 160          // staged L columns (10 N-tiles of 16)
#define RCOLS 208          // staged R columns ([wb-48, wb+160))
#define PITCH 128          // LDS row pitch bytes (64 bf16 = KC)
#define LBYTES (LCOLS * PITCH)          // 20480
#define RBYTES (RCOLS * PITCH)          // 26624
#define SMEM_BYTES (LBYTES + RBYTES)    // 47104 -> 3 blocks/CU by LDS

typedef __bf16 bf16x8 __attribute__((ext_vector_type(8)));
typedef float  f32x4  __attribute__((ext_vector_type(4)));

__device__ __forceinline__ uint32_t pack2_bf16(float a, float b) {
    // RNE f32 -> bf16 pair (a = low half = even c)
    uint32_t ua = __builtin_bit_cast(uint32_t, a);
    uint32_t ub = __builtin_bit_cast(uint32_t, b);
    ua += 0x7FFFu + ((ua >> 16) & 1u);
    ub += 0x7FFFu + ((ub >> 16) & 1u);
    return (ua >> 16) | (ub & 0xFFFF0000u);
}

// Byte offset of the 16B slot holding c-range [8*chi, 8*chi+8) of row lw.
__device__ __forceinline__ int lds_slotoff(int lw, int chi) {
    return lw * PITCH + ((chi ^ (lw & 7) ^ ((lw >> 4) & 7)) << 4);
}

__global__ __launch_bounds__(512, 4)
void psm_cost_volume(const float* __restrict__ lf,
                     const float* __restrict__ rf,
                     float* __restrict__ out) {
    const int half = blockIdx.x;        // 0,1
    const int h    = blockIdx.y;
    const int b    = blockIdx.z;
    const int wb   = half * HALFW;
    const int tid  = threadIdx.x;
    const int lane = tid & 63;
    const int wave = tid >> 6;          // 8 waves
    const int l15  = lane & 15;
    const int l4   = lane >> 4;
    const int jj   = wave & 3;          // A-tile offset
    const int nb   = wave >> 2;         // n = 2*pi + nb

    extern __shared__ char smem[];
    // [0, LBYTES): L tile rows lw=0..159  (w = wb + lw)
    // [LBYTES, +RBYTES): R tile rows lw=0..207 (w' = wb - 48 + lw)
    // epilogue reuses [0, D_*HALFW*4) as f32 out staging

    const float* lbase = lf + (size_t)b * CHW_ + (size_t)h * W_;
    const float* rbase = rf + (size_t)b * CHW_ + (size_t)h * W_;

    f32x4 acc[5];
    #pragma unroll
    for (int i = 0; i < 5; ++i) acc[i] = f32x4{0.f, 0.f, 0.f, 0.f};

    for (int ch = 0; ch < NCHUNK; ++ch) {
        const int c0 = ch * KC;
        if (ch) __syncthreads();   // previous compute done before restage

        // ---- stage L chunk: 32 c-pairs x 40 float4 (= KC x LCOLS fp32) ----
        #pragma unroll
        for (int it = 0; it < 3; ++it) {
            int idx = tid + it * 512;
            if (idx < 32 * 40) {
                int rp = idx / 40;            // c-pair index
                int q  = idx - rp * 40;       // float4 column
                int w4 = wb + 4 * q;
                f32x4 v0 = {0.f, 0.f, 0.f, 0.f}, v1 = {0.f, 0.f, 0.f, 0.f};
                if (w4 + 3 < W_) {
                    const float* g = lbase + (size_t)(c0 + 2 * rp) * HW_ + w4;
                    v0 = *(const f32x4*)g;
                    v1 = *(const f32x4*)(g + HW_);
                }
                const int chi = rp >> 2;
                const int cb  = (rp & 3) << 2;
                #pragma unroll
                for (int j = 0; j < 4; ++j) {
                    int lw = 4 * q + j;
                    *(uint32_t*)(smem + lds_slotoff(lw, chi) + cb) =
                        pack2_bf16(v0[j], v1[j]);
                }
            }
        }
        // ---- stage R chunk: 32 c-pairs x 52 float4 (= KC x RCOLS fp32) ----
        #pragma unroll
        for (int it = 0; it < 4; ++it) {
            int idx = tid + it * 512;
            if (idx < 32 * 52) {
                int rp = idx / 52;
                int q  = idx - rp * 52;
                int w4 = wb - 48 + 4 * q;     // can be negative -> zeros
                f32x4 v0 = {0.f, 0.f, 0.f, 0.f}, v1 = {0.f, 0.f, 0.f, 0.f};
                if (w4 >= 0 && w4 + 3 < W_) {
                    const float* g = rbase + (size_t)(c0 + 2 * rp) * HW_ + w4;
                    v0 = *(const f32x4*)g;
                    v1 = *(const f32x4*)(g + HW_);
                }
                const int chi = rp >> 2;
                const int cb  = (rp & 3) << 2;
                #pragma unroll
                for (int j = 0; j < 4; ++j) {
                    int lw = 4 * q + j;
                    *(uint32_t*)(smem + LBYTES + lds_slotoff(lw, chi) + cb) =
                        pack2_bf16(v0[j], v1[j]);
                }
            }
        }
        __syncthreads();

        // ---- compute: 5 (n,jj) pairs per wave, all reads ds_read_b128 ----
        #pragma unroll
        for (int ks = 0; ks < 2; ++ks) {
            const int chi = ks * 4 + l4;
            #pragma unroll
            for (int pi = 0; pi < 5; ++pi) {
                const int n   = 2 * pi + nb;
                const int lwB = 16 * n + l15;
                const int lwA = 16 * (n + jj) + l15;
                bf16x8 bfrag = *(const bf16x8*)(smem + lds_slotoff(lwB, chi));
                bf16x8 afrag = *(const bf16x8*)(smem + LBYTES + lds_slotoff(lwA, chi));
                acc[pi] = __builtin_amdgcn_mfma_f32_16x16x32_bf16(afrag, bfrag, acc[pi], 0, 0, 0);
            }
        }
    }
    __syncthreads();

    // ---- scatter accumulators -> LDS [D_][HALFW] f32 ----
    // D[m][n]: col tn = l15, row tm = 4*l4 + r.
    // w = wb + 16n + tn ; w' = wb - 48 + 16(n+jj) + tm ; d = 48 - 16*jj + tn - tm
    float* outs = (float*)smem;
    #pragma unroll
    for (int pi = 0; pi < 5; ++pi) {
        const int n  = 2 * pi + nb;
        const int lw = 16 * n + l15;
        #pragma unroll
        for (int r = 0; r < 4; ++r) {
            int tm = 4 * l4 + r;
            int d  = 48 - 16 * jj + l15 - tm;
            if (d >= 0 && d < D_ && lw < HALFW) {
                outs[d * HALFW + lw] = acc[pi][r] * (1.f / 512.f);
            }
        }
    }
    __syncthreads();

    // ---- coalesced global store ----
    float* obase = out + (size_t)b * (D_ * HW_) + (size_t)h * W_ + wb;
    for (int idx = tid; idx < D_ * HALFW; idx += 512) {
        int d  = idx / HALFW;
        int lw = idx - d * HALFW;
        obase[(size_t)d * HW_ + lw] = outs[idx];
    }
}

extern "C" void kernel_launch(void* const* d_in, const int* in_sizes, int n_in,
                              void* d_out, int out_size, void* d_ws, size_t ws_size,
                              hipStream_t stream) {
    const float* lf = (const float*)d_in[0];
    const float* rf = (const float*)d_in[1];
    float* out = (float*)d_out;
    dim3 grid(2, H_, B_);   // 768 blocks
    psm_cost_volume<<<grid, 512, SMEM_BYTES, stream>>>(lf, rf, out);
}